// Round 5
// baseline (143.869 us; speedup 1.0000x reference)
//
#include <hip/hip_runtime.h>
#include <hip/hip_fp16.h>

#define D_ 160
#define H_ 192
#define W_ 160
#define PLANE (H_*W_)          // 30720
#define VOL (D_*PLANE)         // 4915200 per sample
#define NS 2
#define WSZ 729.0f

// B array per sample: 5 quantities (I, J, I*I, J*J, I*J), each VOL fp16,
// layout [q][d][h][w], holding the H,W-box-summed products.

// ---------------- zero accumulators ----------------
__global__ void k_zero(float* acc) {
    if (threadIdx.x < NS) acc[threadIdx.x] = 0.f;
}

// ---------------- pass 1: products + W-sum + H-sum -> fp16 B ----------------
// thread: 8 w (seg) x 4 h-outputs (chunk) x fixed d.
// Running H-sums rs[5][8] in fp32; entering/leaving rows recomputed from the
// fp32 inputs (recompute-subtract: bit-identical -> exact cancellation).
// per sample: seg(20) x chunk(48) x d(160) = 153600 threads = 600 blocks
__global__ __launch_bounds__(256) void k_wh(const float* __restrict__ I,
                                            const float* __restrict__ J,
                                            __half* __restrict__ B, long stride) {
    int b  = blockIdx.x;
    int sl = b / 600;
    int t  = (b % 600) * 256 + threadIdx.x;     // 0..153599
    int seg   = t % 20;
    int chunk = (t / 20) % 48;
    int d     = t / 960;                        // 0..159
    int w0 = seg * 8;
    int h0 = chunk * 4;
    const float* Ib = I + (long)sl * VOL + (long)d * PLANE;
    const float* Jb = J + (long)sl * VOL + (long)d * PLANE;
    __half* Bb = B + (long)sl * stride + (long)d * PLANE + w0;   // + q*VOL + h*W_

    float rs[5][8];
#pragma unroll
    for (int q = 0; q < 5; ++q)
#pragma unroll
        for (int k = 0; k < 8; ++k) rs[q][k] = 0.f;

    // one row's W-window sums for all 5 quantities, accumulated with +/- sign
    auto rowop = [&](int h, float sign) {
        if (h < 0 || h >= H_) return;
        const float* ri = Ib + (long)h * W_;
        const float* rj = Jb + (long)h * W_;
        float vI[16], vJ[16];
#pragma unroll
        for (int bq = 0; bq < 4; ++bq) {
            int f0 = w0 - 4 + 4 * bq;           // multiple of 4 -> aligned
            if (f0 >= 0 && f0 <= W_ - 4) {
                float4 a = *reinterpret_cast<const float4*>(ri + f0);
                float4 c = *reinterpret_cast<const float4*>(rj + f0);
                vI[4*bq+0]=a.x; vI[4*bq+1]=a.y; vI[4*bq+2]=a.z; vI[4*bq+3]=a.w;
                vJ[4*bq+0]=c.x; vJ[4*bq+1]=c.y; vJ[4*bq+2]=c.z; vJ[4*bq+3]=c.w;
            } else {
#pragma unroll
                for (int k = 0; k < 4; ++k) { vI[4*bq+k] = 0.f; vJ[4*bq+k] = 0.f; }
            }
        }
#pragma unroll
        for (int q = 0; q < 5; ++q) {
            float p[16];
#pragma unroll
            for (int i = 0; i < 16; ++i) {
                float a = vI[i], bb = vJ[i];
                p[i] = (q == 0) ? a : (q == 1) ? bb : (q == 2) ? a*a : (q == 3) ? bb*bb : a*bb;
            }
            float o[8];
            float ssum = 0.f;
#pragma unroll
            for (int i = 0; i < 9; ++i) ssum += p[i];
            o[0] = ssum;
#pragma unroll
            for (int k = 1; k < 8; ++k) { ssum += p[k + 8] - p[k - 1]; o[k] = ssum; }
#pragma unroll
            for (int k = 0; k < 8; ++k) rs[q][k] += sign * o[k];
        }
    };

    // init window rows [h0-4, h0+3]
    for (int i = 0; i < 8; ++i) rowop(h0 - 4 + i, 1.f);

    for (int hh = 0; hh < 4; ++hh) {
        int h = h0 + hh;
        rowop(h + 4, 1.f);                       // window now [h-4, h+4]
#pragma unroll
        for (int q = 0; q < 5; ++q) {
            union { __half hv[8]; int4 v; } u;
#pragma unroll
            for (int k = 0; k < 8; ++k) u.hv[k] = __float2half(rs[q][k]);
            *reinterpret_cast<int4*>(Bb + (long)q * VOL + (long)h * W_) = u.v;
        }
        rowop(h - 4, -1.f);                      // prep next: [h-3, h+4]
    }
}

// ---------------- pass 2: D-axis 9-box-sum + cc + reduction ----------------
// thread: 8 consecutive w (int4 fp16 loads), fixed h, d-chunk of 5.
// No ring: slide via add(d+5)/sub(d-4) re-loads (L2/L3 hits, exact cancel).
// per sample: wseg(20) x h(192) x chunk(32) = 122880 threads = 480 blocks
__global__ __launch_bounds__(256) void k_d(const __half* __restrict__ B,
                                           float* __restrict__ acc, long stride) {
    int b  = blockIdx.x;
    int sl = b / 480;
    int t  = (b % 480) * 256 + threadIdx.x;     // 0..122879
    int ws    = t % 20;
    int h     = (t / 20) % 192;
    int chunk = t / 3840;                       // 0..31
    int d0 = chunk * 5;
    const __half* Bb = B + (long)sl * stride + (long)h * W_ + ws * 8;  // + q*VOL + d*PLANE

    float s[5][8];
#pragma unroll
    for (int q = 0; q < 5; ++q)
#pragma unroll
        for (int k = 0; k < 8; ++k) s[q][k] = 0.f;

    // accumulate one d-plane row (8 fp16) into sq[*] with sign; static s-indexing
    auto plane = [&](float (&sq)[8], int q, int d, float sign) {
        if (d < 0 || d >= D_) return;
        union { __half hv[8]; int4 v; } u;
        u.v = *reinterpret_cast<const int4*>(Bb + (long)q * VOL + (long)d * PLANE);
#pragma unroll
        for (int k = 0; k < 8; ++k) sq[k] += sign * __half2float(u.hv[k]);
    };

    // init window [d0-4, d0+4]
#pragma unroll
    for (int q = 0; q < 5; ++q)
        for (int i = -4; i <= 4; ++i) plane(s[q], q, d0 + i, 1.f);

    float local = 0.f;
    for (int dd = 0; dd < 5; ++dd) {
#pragma unroll
        for (int k = 0; k < 8; ++k) {
            float Is = s[0][k], Js = s[1][k], I2 = s[2][k], J2 = s[3][k], IJ = s[4][k];
            float uI = Is * (1.f / WSZ), uJ = Js * (1.f / WSZ);
            float cross = IJ - uJ * Is - uI * Js + uI * uJ * WSZ;
            float Iv = I2 - 2.f * uI * Is + uI * uI * WSZ;
            float Jv = J2 - 2.f * uJ * Js + uJ * uJ * WSZ;
            local += 1.f - cross * cross / (Iv * Jv + 1e-5f);
        }
        int da = d0 + dd + 5, dsu = d0 + dd - 4;
#pragma unroll
        for (int q = 0; q < 5; ++q) { plane(s[q], q, da, 1.f); plane(s[q], q, dsu, -1.f); }
    }

    __shared__ float red[256];
    red[threadIdx.x] = local;
    __syncthreads();
    for (int off = 128; off > 0; off >>= 1) {
        if (threadIdx.x < off) red[threadIdx.x] += red[threadIdx.x + off];
        __syncthreads();
    }
    if (threadIdx.x == 0) atomicAdd(acc + sl, red[0]);
}

// ---------------- finalize ----------------
__global__ void k_fin(const float* __restrict__ acc, float* __restrict__ out) {
    if (threadIdx.x < NS) out[threadIdx.x] = acc[threadIdx.x] * (1.f / (float)VOL);
}

extern "C" void kernel_launch(void* const* d_in, const int* in_sizes, int n_in,
                              void* d_out, int out_size, void* d_ws, size_t ws_size,
                              hipStream_t stream) {
    const float* J = (const float*)d_in[0];   // y_pred
    const float* I = (const float*)d_in[1];   // y_true
    float* out = (float*)d_out;
    __half* B  = (__half*)d_ws;               // 2 samples x 5*VOL fp16 = 98.3 MB

    const long SAMP = 5L * VOL;               // B elements per sample
    float* acc = (float*)((char*)d_ws + (size_t)(NS * SAMP) * sizeof(__half));

    k_zero<<<1, 64, 0, stream>>>(acc);
    k_wh<<<NS * 600, 256, 0, stream>>>(I, J, B, SAMP);
    k_d<<<NS * 480, 256, 0, stream>>>(B, acc, SAMP);
    k_fin<<<1, 64, 0, stream>>>(acc, out);
}

// Round 6
// 126.780 us; speedup vs baseline: 1.1348x; 1.1348x over previous
//
#include <hip/hip_runtime.h>
#include <hip/hip_fp16.h>

#define D_ 160
#define H_ 192
#define W_ 160
#define PLANE (H_*W_)          // 30720
#define VOL (D_*PLANE)         // 4915200 per sample
#define NS 2
#define WSZ 729.0f
#define DC 20                  // d-outputs per k_d thread

// B per sample: 5 quantities (I, J, I*I, J*J, I*J), each VOL fp16,
// layout [q][d][h][w], holding HW-box-summed products.

__global__ void k_zero(float* acc) {
    if (threadIdx.x < NS) acc[threadIdx.x] = 0.f;
}

// ---------------- pass 1: products + W-sum + H-sum -> fp16 B ----------------
// q-split: grp0 threads compute {I, I^2, I*J} (planes 0,2,4), grp1 {J, J^2}
// (planes 1,3). Same rowop count per output as r4 (h-chunk=8), 2x threads.
// grid: grp(2) x sample(2) x 300 blocks = 1200 blocks
__device__ __forceinline__ void slide9(const float (&p)[16], float (&acc)[8], float sign) {
    float o[8];
    float ssum = 0.f;
#pragma unroll
    for (int i = 0; i < 9; ++i) ssum += p[i];
    o[0] = ssum;
#pragma unroll
    for (int k = 1; k < 8; ++k) { ssum += p[k + 8] - p[k - 1]; o[k] = ssum; }
#pragma unroll
    for (int k = 0; k < 8; ++k) acc[k] += sign * o[k];
}

__global__ __launch_bounds__(256) void k_wh(const float* __restrict__ I,
                                            const float* __restrict__ J,
                                            __half* __restrict__ B, long stride) {
    int b   = blockIdx.x;
    int grp = b / 600;                          // 0 or 1 (uniform per block)
    int b2  = b % 600;
    int sl  = b2 / 300;
    int t   = (b2 % 300) * 256 + threadIdx.x;   // 0..76799
    int seg   = t % 20;
    int chunk = (t / 20) % 24;
    int d     = t / 480;                        // 0..159
    int w0 = seg * 8;
    int h0 = chunk * 8;
    const float* Ib = I + (long)sl * VOL + (long)d * PLANE;
    const float* Jb = J + (long)sl * VOL + (long)d * PLANE;
    __half* Bb = B + (long)sl * stride + (long)d * PLANE + w0;

    if (grp == 0) {
        float rs[3][8];                         // I, I^2, I*J
#pragma unroll
        for (int q = 0; q < 3; ++q)
#pragma unroll
            for (int k = 0; k < 8; ++k) rs[q][k] = 0.f;

        auto rowop = [&](int h, float sign) {
            if (h < 0 || h >= H_) return;
            const float* ri = Ib + (long)h * W_;
            const float* rj = Jb + (long)h * W_;
            float vI[16], vJ[16];
#pragma unroll
            for (int bq = 0; bq < 4; ++bq) {
                int f0 = w0 - 4 + 4 * bq;
                if (f0 >= 0 && f0 <= W_ - 4) {
                    float4 a = *reinterpret_cast<const float4*>(ri + f0);
                    float4 c = *reinterpret_cast<const float4*>(rj + f0);
                    vI[4*bq+0]=a.x; vI[4*bq+1]=a.y; vI[4*bq+2]=a.z; vI[4*bq+3]=a.w;
                    vJ[4*bq+0]=c.x; vJ[4*bq+1]=c.y; vJ[4*bq+2]=c.z; vJ[4*bq+3]=c.w;
                } else {
#pragma unroll
                    for (int k = 0; k < 4; ++k) { vI[4*bq+k] = 0.f; vJ[4*bq+k] = 0.f; }
                }
            }
            float p[16];
#pragma unroll
            for (int i = 0; i < 16; ++i) p[i] = vI[i];
            slide9(p, rs[0], sign);
#pragma unroll
            for (int i = 0; i < 16; ++i) p[i] = vI[i] * vI[i];
            slide9(p, rs[1], sign);
#pragma unroll
            for (int i = 0; i < 16; ++i) p[i] = vI[i] * vJ[i];
            slide9(p, rs[2], sign);
        };

        for (int i = 0; i < 8; ++i) rowop(h0 - 4 + i, 1.f);
        for (int hh = 0; hh < 8; ++hh) {
            int h = h0 + hh;
            rowop(h + 4, 1.f);
            const int plane[3] = {0, 2, 4};
#pragma unroll
            for (int q = 0; q < 3; ++q) {
                union { __half hv[8]; int4 v; } u;
#pragma unroll
                for (int k = 0; k < 8; ++k) u.hv[k] = __float2half(rs[q][k]);
                *reinterpret_cast<int4*>(Bb + (long)plane[q] * VOL + (long)h * W_) = u.v;
            }
            rowop(h - 4, -1.f);
        }
    } else {
        float rs[2][8];                         // J, J^2
#pragma unroll
        for (int q = 0; q < 2; ++q)
#pragma unroll
            for (int k = 0; k < 8; ++k) rs[q][k] = 0.f;

        auto rowop = [&](int h, float sign) {
            if (h < 0 || h >= H_) return;
            const float* rj = Jb + (long)h * W_;
            float vJ[16];
#pragma unroll
            for (int bq = 0; bq < 4; ++bq) {
                int f0 = w0 - 4 + 4 * bq;
                if (f0 >= 0 && f0 <= W_ - 4) {
                    float4 c = *reinterpret_cast<const float4*>(rj + f0);
                    vJ[4*bq+0]=c.x; vJ[4*bq+1]=c.y; vJ[4*bq+2]=c.z; vJ[4*bq+3]=c.w;
                } else {
#pragma unroll
                    for (int k = 0; k < 4; ++k) vJ[4*bq+k] = 0.f;
                }
            }
            float p[16];
#pragma unroll
            for (int i = 0; i < 16; ++i) p[i] = vJ[i];
            slide9(p, rs[0], sign);
#pragma unroll
            for (int i = 0; i < 16; ++i) p[i] = vJ[i] * vJ[i];
            slide9(p, rs[1], sign);
        };

        for (int i = 0; i < 8; ++i) rowop(h0 - 4 + i, 1.f);
        for (int hh = 0; hh < 8; ++hh) {
            int h = h0 + hh;
            rowop(h + 4, 1.f);
            const int plane[2] = {1, 3};
#pragma unroll
            for (int q = 0; q < 2; ++q) {
                union { __half hv[8]; int4 v; } u;
#pragma unroll
                for (int k = 0; k < 8; ++k) u.hv[k] = __float2half(rs[q][k]);
                *reinterpret_cast<int4*>(Bb + (long)plane[q] * VOL + (long)h * W_) = u.v;
            }
            rowop(h - 4, -1.f);
        }
    }
}

// ---------------- pass 2: D-axis 9-box-sum + cc + reduction ----------------
// q-split ring: thread (q, ws, h, chunk) owns ONE quantity, 8 w, DC=20 d-outputs.
// 10-slot int4 ring (statically indexed, full unroll) -> each B element read
// once + init halo (1.45x). 5 q-waves per 320-thread block exchange window
// sums via double-buffered LDS each d-step; cc outputs split 2/2/2/1/1.
// blocks: 480/sample -> 960
__device__ __forceinline__ float ccf(float Is, float Js, float I2, float J2, float IJ) {
    float uI = Is * (1.f / WSZ), uJ = Js * (1.f / WSZ);
    float cross = IJ - uJ * Is - uI * Js + uI * uJ * WSZ;
    float Iv = I2 - 2.f * uI * Is + uI * uI * WSZ;
    float Jv = J2 - 2.f * uJ * Js + uJ * uJ * WSZ;
    return 1.f - cross * cross / (Iv * Jv + 1e-5f);
}

__global__ __launch_bounds__(320) void k_d(const __half* __restrict__ B,
                                           float* __restrict__ acc, long stride) {
    __shared__ float xch[2 * 5 * 64 * 8];      // 20 KB, double-buffered
    __shared__ float red[320];
    int b   = blockIdx.x;
    int sl  = b / 480;
    int tid = threadIdx.x;
    int q   = tid >> 6;                        // wave index = quantity
    int s   = tid & 63;
    int gs  = (b % 480) * 64 + s;              // 0..30719
    int ws    = gs % 20;
    int h     = (gs / 20) % 192;
    int chunk = gs / 3840;                     // 0..7
    int d0 = chunk * DC;
    const __half* Bq = B + (long)sl * stride + (long)q * VOL + (long)h * W_ + ws * 8;

    int4 z; z.x = z.y = z.z = z.w = 0;
    int4 ring[10];
    ring[0] = z;
    float S[8];
#pragma unroll
    for (int k = 0; k < 8; ++k) S[k] = 0.f;

    // init: slots 1..9 hold d = d0-5 .. d0+3 ; S = their sum
#pragma unroll
    for (int j = 1; j <= 9; ++j) {
        int dd_ = d0 + j - 6;
        int4 v = z;
        if (dd_ >= 0) v = *reinterpret_cast<const int4*>(Bq + (long)dd_ * PLANE);
        ring[j] = v;
        union { int4 v; __half hh[8]; } u; u.v = v;
#pragma unroll
        for (int k = 0; k < 8; ++k) S[k] += __half2float(u.hh[k]);
    }

    int c0  = (q < 3) ? 2 * q : 3 + q;         // 0,2,4,6,7
    int cnt = (q < 3) ? 2 : 1;
    float local = 0.f;

#pragma unroll
    for (int dd = 0; dd < DC; ++dd) {
        int dn = d0 + dd + 4;
        int4 v = z;
        if (dn < D_) v = *reinterpret_cast<const int4*>(Bq + (long)dn * PLANE);
        union { int4 v; __half hh[8]; } un, uo;
        un.v = v; uo.v = ring[(dd + 1) % 10];
#pragma unroll
        for (int k = 0; k < 8; ++k) S[k] += __half2float(un.hh[k]) - __half2float(uo.hh[k]);
        ring[dd % 10] = v;

        float* buf = xch + (dd & 1) * 2560 + q * 512 + s * 8;
#pragma unroll
        for (int k = 0; k < 8; ++k) buf[k] = S[k];
        __syncthreads();

        const float* rb = xch + (dd & 1) * 2560 + s * 8;
        float A0[5], A1[5];
#pragma unroll
        for (int qq = 0; qq < 5; ++qq) {
            A0[qq] = rb[qq * 512 + c0];
            A1[qq] = (cnt == 2) ? rb[qq * 512 + c0 + 1] : 0.f;
        }
        local += ccf(A0[0], A0[1], A0[2], A0[3], A0[4]);
        if (cnt == 2) local += ccf(A1[0], A1[1], A1[2], A1[3], A1[4]);
    }

    red[tid] = local;
    __syncthreads();
    for (int off = 160; off >= 5; off >>= 1) {
        if (tid < off) red[tid] += red[tid + off];
        __syncthreads();
    }
    if (tid == 0) {
        float r = red[0] + red[1] + red[2] + red[3] + red[4];
        atomicAdd(acc + sl, r);
    }
}

__global__ void k_fin(const float* __restrict__ acc, float* __restrict__ out) {
    if (threadIdx.x < NS) out[threadIdx.x] = acc[threadIdx.x] * (1.f / (float)VOL);
}

extern "C" void kernel_launch(void* const* d_in, const int* in_sizes, int n_in,
                              void* d_out, int out_size, void* d_ws, size_t ws_size,
                              hipStream_t stream) {
    const float* J = (const float*)d_in[0];   // y_pred
    const float* I = (const float*)d_in[1];   // y_true
    float* out = (float*)d_out;
    __half* B  = (__half*)d_ws;               // 2 samples x 5*VOL fp16 = 98.3 MB

    const long SAMP = 5L * VOL;
    float* acc = (float*)((char*)d_ws + (size_t)(NS * SAMP) * sizeof(__half));

    k_zero<<<1, 64, 0, stream>>>(acc);
    k_wh<<<1200, 256, 0, stream>>>(I, J, B, SAMP);
    k_d<<<960, 320, 0, stream>>>(B, acc, SAMP);
    k_fin<<<1, 64, 0, stream>>>(acc, out);
}